// Round 6
// baseline (197.442 us; speedup 1.0000x reference)
//
#include <hip/hip_runtime.h>
#include <hip/hip_bf16.h>

// BagOfWords: input [1024, 512] int32 tokens in [0, 50257).
// Output [1024, 50256] float32: per-row histogram, vocab bin 0 dropped.
//
// u16-packed LDS histogram: counts <= 512 fit u16, two bins per u32 word,
// incremented with atomicAdd(word, 1 or 1<<16) -- no cross-bin overflow
// possible. Half the vocab per block (25128 bins = 50.25 KB LDS) -> 3
// blocks/CU resident, phases overlap across blocks. Each block: zero LDS,
// scan its row's 512 tokens ONCE, then one long uninterrupted coalesced
// store burst (100.5 KB, ~12 float4 per thread, no barriers inside).
// Timing model (R1-R5): bench dur = ~123us harness poison-fill (fixed)
// + kernel; this targets the kernel's 74us -> ~40us.

#define BATCH 1024
#define SEQ 512
#define VOCAB 50257
#define OUT_COLS (VOCAB - 1)       // 50256
#define HALF_BINS (OUT_COLS / 2)   // 25128 bins per block
#define NWORDS (HALF_BINS / 2)     // 12564 u32 words (2 bins/word)
#define BLOCK 512

__global__ __launch_bounds__(BLOCK) void bow_row_kernel(
    const int* __restrict__ tokens, float* __restrict__ out) {
    __shared__ unsigned int packed[NWORDS];  // 50256 B

    const int half = blockIdx.x;             // 0 or 1
    const int b    = blockIdx.y;             // row
    const int t    = threadIdx.x;
    const int c0   = half * HALF_BINS;       // bin range [c0, c0+25128)

    // Zero LDS: 12564 words = 3141 uint4s, ~6 per thread.
    const uint4 z = make_uint4(0u, 0u, 0u, 0u);
    for (int i = t; i < NWORDS / 4; i += BLOCK) ((uint4*)packed)[i] = z;
    __syncthreads();

    // Histogram: each thread loads one token of this row (512 = BLOCK).
    {
        int tok = tokens[b * SEQ + t];
        unsigned int bin = (unsigned int)(tok - 1 - c0);  // tok==0 underflows
        if (bin < HALF_BINS)
            atomicAdd(&packed[bin >> 1], (bin & 1) ? 0x10000u : 1u);
    }
    __syncthreads();

    // Stream out: 4 consecutive bins per thread per iter (one uint2 LDS read
    // -> one coalesced float4 store). 25128 = 12*2048 + 552; threads t<138
    // do a 13th iteration.
    float* orow = out + (size_t)b * OUT_COLS + c0;
    for (int i = t * 4; i < HALF_BINS; i += BLOCK * 4) {
        uint2 w = *(const uint2*)&packed[i >> 1];
        float4 v = make_float4((float)(w.x & 0xffffu), (float)(w.x >> 16),
                               (float)(w.y & 0xffffu), (float)(w.y >> 16));
        *(float4*)(orow + i) = v;
    }
}

extern "C" void kernel_launch(void* const* d_in, const int* in_sizes, int n_in,
                              void* d_out, int out_size, void* d_ws, size_t ws_size,
                              hipStream_t stream) {
    const int* tokens = (const int*)d_in[0];
    float* out = (float*)d_out;

    dim3 grid(2, BATCH);   // (half, row) = 2048 blocks
    bow_row_kernel<<<grid, BLOCK, 0, stream>>>(tokens, out);
}